// Round 4
// baseline (1608.172 us; speedup 1.0000x reference)
//
#include <hip/hip_runtime.h>
#include <hip/hip_bf16.h>
#include <stdint.h>

// B=16, C=1024, D=H=W=8 -> N=512 tokens, 27 taps
#define BATCH 16
#define CCH   1024
#define NTOK  512
#define NKT   432   // K-tiles: 27 taps * (1024/64)

typedef _Float16 f16_t;
typedef f16_t f16x8 __attribute__((ext_vector_type(8)));
typedef f16_t f16x4 __attribute__((ext_vector_type(4)));
typedef float f32x4 __attribute__((ext_vector_type(4)));

#define GAS __attribute__((address_space(1)))
#define LAS __attribute__((address_space(3)))

__device__ __forceinline__ void gload_lds16(const void* g, void* l) {
  __builtin_amdgcn_global_load_lds((const GAS uint32_t*)g, (LAS uint32_t*)l, 16, 0, 0);
}

// ---------------- cast + transpose: [B][C][N] f32 -> [B][N][C] f16 -----------
__global__ __launch_bounds__(256) void cast_transpose_kernel(
    const float* __restrict__ src, f16_t* __restrict__ dst) {
  __shared__ float tile[64][65];
  const int b  = blockIdx.z;
  const int c0 = blockIdx.y * 64;
  const int n0 = blockIdx.x * 64;
  const int col  = threadIdx.x & 63;
  const int row4 = threadIdx.x >> 6;
  const float* s = src + ((size_t)b * CCH + c0) * NTOK + n0;
#pragma unroll
  for (int r = 0; r < 64; r += 4)
    tile[r + row4][col] = s[(size_t)(r + row4) * NTOK + col];
  __syncthreads();
  f16_t* d = dst + ((size_t)b * NTOK + n0) * CCH + c0;
#pragma unroll
  for (int r = 0; r < 64; r += 4)
    d[(size_t)(r + row4) * CCH + col] = (f16_t)tile[col][r + row4];
}

// -------- weight transpose: [O][I][27] f32 -> rows o_base+o of [27][3072][1024] f16
__global__ __launch_bounds__(256) void wtrans_kernel(
    const float* __restrict__ w, f16_t* __restrict__ wt, const int o_base) {
  __shared__ float buf[64 * 27];
  const int o  = blockIdx.x;
  const int i0 = blockIdx.y * 64;
  const float* s = w + (size_t)o * (CCH * 27) + (size_t)i0 * 27;
  for (int idx = threadIdx.x; idx < 64 * 27; idx += 256) buf[idx] = s[idx];
  __syncthreads();
  for (int idx = threadIdx.x; idx < 64 * 27; idx += 256) {
    const int t = idx >> 6;
    const int i = idx & 63;
    wt[((size_t)t * 3072 + o_base + o) * 1024 + i0 + i] = (f16_t)buf[i * 27 + t];
  }
}

// ---------------- fused QKV conv: 27*16 shifted GEMM K-tiles -----------------
// BM=256 x BN=128, BK=64, 8 waves (4M x 2N), 2 phases/K-tile, 16 MFMA/phase.
// 3-set LDS ring (48KB/set = A 32K + B 16K): tile t reads set t%3, stages
// target set (t+2)%3 -> no read/write aliasing; one counted vmcnt(6)/K-tile.
// Swizzle: 16B slot s of each 64B row stored at slot s ^ ((row>>1)&3)
// (applied on the global SOURCE address; LDS dest stays linear; read applies
// the same XOR). Grid 768 = 3 balanced rounds of 256 CUs; XCD mapping groups
// same-m-panel blocks per XCD for weight L2 reuse.
__global__ __launch_bounds__(512, 2) void conv_fused_kernel(
    const f16_t* __restrict__ x_t, const f16_t* __restrict__ y_t,
    const f16_t* __restrict__ wcat, const float* __restrict__ bcat,
    f16_t* __restrict__ qb, f16_t* __restrict__ kb, f16_t* __restrict__ vb,
    const char* __restrict__ zp) {
  __shared__ char lds[147456];
  const int tid  = threadIdx.x;
  const int lane = tid & 63;
  const int wid  = tid >> 6;
  const int wr = wid >> 1, wc = wid & 1;   // 4 M-waves x 2 N-waves

  // XCD-grouped mapping: xcd = id%8 serves contiguous linear range ->
  // each weight m-panel touched by <=2 XCDs; 32 same-panel blocks per round.
  const int id = blockIdx.x;
  const int linear = (id & 7) * 96 + (id >> 3);
  const int m_tile = linear >> 6;          // 0..11
  const int n_tile = linear & 63;          // 0..63
  const int m0  = m_tile * 256;            // fused C_out base (0..3071)
  const int bn0 = n_tile * 128;
  const int b   = bn0 >> 9;
  const int n0  = bn0 & 511;
  const int sec = m_tile >> 2;             // 0=q,1=k,2=v
  const char* src_c  = (const char*)((sec == 0) ? x_t : y_t) + (size_t)b * NTOK * 2048;
  const char* wcat_c = (const char*)wcat;

  // staging: thread covers (row = tid>>2, slot = tid&3) of a 128-row block
  const int slotsrc16 = (((tid & 3) ^ ((tid >> 3) & 3)) << 4);
  const int tid16 = tid << 4;
  const int r0 = tid >> 2;                 // 0..127
  const size_t arow0 = (size_t)(m0 + r0) * 2048 + slotsrc16;
  const size_t arow1 = arow0 + (size_t)128 * 2048;
  int cur_kt = -1;
  const char* bp0 = zp;

  // fragment-read constants
  const int fr = lane & 15;
  const int rdbase = fr * 64 + ((((lane >> 4) ^ ((fr >> 1) & 3))) << 4);

  f32x4 acc[4][4] = {};

  auto stageA = [&](int tt, int kh, int setb) {   // 2 issues: 256 rows x 32 f16
    const int te = (tt < NKT) ? tt : tt - 3;      // tail remap: same ring set
    const size_t go = (size_t)(te >> 4) * (size_t)(3072 * 2048) +
                      ((size_t)(te & 15) << 7) + ((size_t)kh << 6);
    char* ldst = lds + setb + (kh << 14) + tid16;
    gload_lds16(wcat_c + go + arow0, ldst);
    gload_lds16(wcat_c + go + arow1, ldst + 8192);
  };
  auto upd_tap = [&](int kt) {
    cur_kt = kt;
    const int kd = kt / 9, rem = kt % 9, khh = rem / 3, kww = rem % 3;
    const int n = n0 + r0;
    const int d = (n >> 6) + kd - 1;
    const int h = ((n >> 3) & 7) + khh - 1;
    const int w = (n & 7) + kww - 1;
    const bool ok = ((unsigned)d < 8u) & ((unsigned)h < 8u) & ((unsigned)w < 8u);
    const int nsrc = (d << 6) + (h << 3) + w;
    bp0 = ok ? src_c + (size_t)nsrc * 2048 : zp;
  };
  auto stageB = [&](int tt, int kh, int setb) {   // 1 issue: 128 rows x 32 f16
    const int te = (tt < NKT) ? tt : tt - 3;
    const int kt = te >> 4;
    if (kt != cur_kt) upd_tap(kt);
    const int go = ((te & 15) << 7) + (kh << 6) + slotsrc16;
    char* ldst = lds + setb + 32768 + (kh << 13) + tid16;
    gload_lds16(bp0 + go, ldst);
  };

  // prologue: tile0 -> set0, tile1 -> set1 (12 issues); drain tile0 (keep 6)
  stageA(0, 0, 0);     stageB(0, 0, 0);
  stageA(0, 1, 0);     stageB(0, 1, 0);
  stageA(1, 0, 49152); stageB(1, 0, 49152);
  stageA(1, 1, 49152); stageB(1, 1, 49152);
  asm volatile("s_waitcnt vmcnt(6)\n\ts_barrier" ::: "memory");

#define MFMA16(AV, BV)                                                         \
  _Pragma("unroll") for (int i = 0; i < 4; ++i) {                              \
    _Pragma("unroll") for (int j = 0; j < 4; ++j)                              \
        acc[i][j] = __builtin_amdgcn_mfma_f32_16x16x32_f16(                    \
            AV[i], BV[j], acc[i][j], 0, 0, 0);                                 \
  }

  int sb0 = 0, sb1 = 49152, sb2 = 98304;
#pragma unroll 1
  for (int t = 0; t < NKT; ++t) {
    const char* sA = lds + sb0 + wr * 4096 + rdbase;           // A: rows wr*64..
    const char* sB = lds + sb0 + 32768 + wc * 4096 + rdbase;   // B: rows wc*64..
    f16x8 av[4], bv[4];
    // ---- phase 0: k-half 0; stage tile(t+2) k0 pieces into set sb2
#pragma unroll
    for (int i = 0; i < 4; ++i) av[i] = *(const f16x8*)(sA + i * 1024);
#pragma unroll
    for (int j = 0; j < 4; ++j) bv[j] = *(const f16x8*)(sB + j * 1024);
    stageA(t + 2, 0, sb2);
    stageB(t + 2, 0, sb2);
    __builtin_amdgcn_s_barrier();
    __builtin_amdgcn_s_setprio(1);
    MFMA16(av, bv)
    __builtin_amdgcn_s_setprio(0);
    __builtin_amdgcn_s_barrier();
    // ---- phase 1: k-half 1; stage tile(t+2) k1 pieces; counted vmcnt
#pragma unroll
    for (int i = 0; i < 4; ++i) av[i] = *(const f16x8*)(sA + 16384 + i * 1024);
#pragma unroll
    for (int j = 0; j < 4; ++j) bv[j] = *(const f16x8*)(sB + 8192 + j * 1024);
    stageA(t + 2, 1, sb2);
    stageB(t + 2, 1, sb2);
    __builtin_amdgcn_s_barrier();
    __builtin_amdgcn_s_setprio(1);
    MFMA16(av, bv)
    __builtin_amdgcn_s_setprio(0);
    asm volatile("s_waitcnt vmcnt(6)\n\ts_barrier" ::: "memory");
    const int tmp = sb0; sb0 = sb1; sb1 = sb2; sb2 = tmp;
  }
#undef MFMA16

  // epilogue: C frag col=lane&15 -> token n, row=(lane>>4)*4+reg -> channel
  const int msec = (m_tile & 3) * 256;
  const int rq = (lane >> 4) << 2;
#pragma unroll
  for (int i = 0; i < 4; ++i) {
    const int cbase = msec + wr * 64 + i * 16 + rq;
    const float4 bs = *(const float4*)&bcat[m0 + wr * 64 + i * 16 + rq];
    if (sec < 2) {
      f16_t* out = (sec == 0) ? qb : kb;
#pragma unroll
      for (int j = 0; j < 4; ++j) {
        const int n = n0 + wc * 64 + j * 16 + fr;
        f16x4 pk;
        pk[0] = (f16_t)(acc[i][j][0] + bs.x);
        pk[1] = (f16_t)(acc[i][j][1] + bs.y);
        pk[2] = (f16_t)(acc[i][j][2] + bs.z);
        pk[3] = (f16_t)(acc[i][j][3] + bs.w);
        *(f16x4*)(out + ((size_t)(b * NTOK + n)) * CCH + cbase) = pk;
      }
    } else {
      const float bb[4] = {bs.x, bs.y, bs.z, bs.w};
#pragma unroll
      for (int reg = 0; reg < 4; ++reg) {
        f16_t* dst = vb + ((size_t)b * CCH + cbase + reg) * NTOK;
#pragma unroll
        for (int j = 0; j < 4; ++j) {
          const int n = n0 + wc * 64 + j * 16 + fr;
          dst[n] = (f16_t)(acc[i][j][reg] + bb[reg]);
        }
      }
    }
  }
}

// ---------------- generic gemm_bt for attention: C = A * Bt^T (+resid) -------
__global__ __launch_bounds__(256) void attn_gemm_kernel(
    const f16_t* __restrict__ A, const f16_t* __restrict__ Bt,
    float* __restrict__ Cout, const float* __restrict__ resid,
    const int Kdim, const int ldc,
    const size_t strideA, const size_t strideB, const size_t strideC) {
  __shared__ f16_t As[128 * 64];
  __shared__ f16_t Bs[128 * 64];
  char* As_c = (char*)As;
  char* Bs_c = (char*)Bs;

  const int tid  = threadIdx.x;
  const int lane = tid & 63;
  const int wave = tid >> 6;
  const int wr = wave >> 1, wc = wave & 1;
  const int bz = blockIdx.z;
  const int m0 = blockIdx.y * 128;
  const int n0 = blockIdx.x * 128;

  const f16_t* Ab = A + (size_t)bz * strideA;
  const f16_t* Bb = Bt + (size_t)bz * strideB;

  const int rowb = tid >> 3;
  const int colb = (tid & 7) * 16;

  const char* ap[4];
  const char* bp[4];
#pragma unroll
  for (int r = 0; r < 4; ++r) {
    const int row = r * 32 + rowb;
    ap[r] = (const char*)(Ab + (size_t)(m0 + row) * Kdim) + colb;
    bp[r] = (const char*)(Bb + (size_t)(n0 + row) * Kdim) + colb;
  }

  f32x4 acc[4][4] = {};
  const int fr = lane & 15;
  const int fk = (lane >> 4) << 3;

  for (int k0 = 0; k0 < Kdim; k0 += 64) {
#pragma unroll
    for (int r = 0; r < 4; ++r)
      gload_lds16(ap[r], As_c + r * 4096 + wave * 1024);
#pragma unroll
    for (int r = 0; r < 4; ++r)
      gload_lds16(bp[r], Bs_c + r * 4096 + wave * 1024);
#pragma unroll
    for (int r = 0; r < 4; ++r) { ap[r] += 128; bp[r] += 128; }
    __syncthreads();
#pragma unroll
    for (int ks = 0; ks < 2; ++ks) {
      const int kc = ks * 32 + fk;
      f16x8 av[4], bv[4];
#pragma unroll
      for (int i = 0; i < 4; ++i)
        av[i] = *(const f16x8*)&As[(wr * 64 + i * 16 + fr) * 64 + kc];
#pragma unroll
      for (int i = 0; i < 4; ++i)
        bv[i] = *(const f16x8*)&Bs[(wc * 64 + i * 16 + fr) * 64 + kc];
#pragma unroll
      for (int i = 0; i < 4; ++i)
#pragma unroll
        for (int j = 0; j < 4; ++j)
          acc[i][j] = __builtin_amdgcn_mfma_f32_16x16x32_f16(av[i], bv[j], acc[i][j], 0, 0, 0);
    }
    __syncthreads();
  }

  const int mo = m0 + wr * 64 + ((lane >> 4) << 2);
  const int nn = n0 + wc * 64 + (lane & 15);
  float* Cb = Cout + (size_t)bz * strideC;
  const float* Rb = resid ? resid + (size_t)bz * strideC : nullptr;
#pragma unroll
  for (int i = 0; i < 4; ++i) {
#pragma unroll
    for (int j = 0; j < 4; ++j) {
      const int n = nn + j * 16;
#pragma unroll
      for (int reg = 0; reg < 4; ++reg) {
        const int m = mo + i * 16 + reg;
        float v = acc[i][j][reg];
        if (Rb) v += Rb[(size_t)m * ldc + n];
        Cb[(size_t)m * ldc + n] = v;
      }
    }
  }
}

// ---------------- row softmax: S fp32 [rows][512] -> P f16 -------------------
__global__ __launch_bounds__(256) void softmax_kernel(
    const float* __restrict__ S, f16_t* __restrict__ P) {
  const int row  = blockIdx.x * 4 + (threadIdx.x >> 6);
  const int lane = threadIdx.x & 63;
  const float* s = S + (size_t)row * 512;
  const float4 v0 = ((const float4*)s)[lane];
  const float4 v1 = ((const float4*)s)[64 + lane];
  float m = fmaxf(fmaxf(fmaxf(v0.x, v0.y), fmaxf(v0.z, v0.w)),
                  fmaxf(fmaxf(v1.x, v1.y), fmaxf(v1.z, v1.w)));
#pragma unroll
  for (int o = 32; o; o >>= 1) m = fmaxf(m, __shfl_xor(m, o, 64));
  float e[8];
  e[0] = __expf(v0.x - m); e[1] = __expf(v0.y - m);
  e[2] = __expf(v0.z - m); e[3] = __expf(v0.w - m);
  e[4] = __expf(v1.x - m); e[5] = __expf(v1.y - m);
  e[6] = __expf(v1.z - m); e[7] = __expf(v1.w - m);
  float sum = ((e[0] + e[1]) + (e[2] + e[3])) + ((e[4] + e[5]) + (e[6] + e[7]));
#pragma unroll
  for (int o = 32; o; o >>= 1) sum += __shfl_xor(sum, o, 64);
  const float r = 1.0f / sum;
  f16_t* p = P + (size_t)row * 512;
  f16x4 o0, o1;
  o0[0] = (f16_t)(e[0] * r); o0[1] = (f16_t)(e[1] * r);
  o0[2] = (f16_t)(e[2] * r); o0[3] = (f16_t)(e[3] * r);
  o1[0] = (f16_t)(e[4] * r); o1[1] = (f16_t)(e[5] * r);
  o1[2] = (f16_t)(e[6] * r); o1[3] = (f16_t)(e[7] * r);
  ((f16x4*)p)[lane] = o0;
  ((f16x4*)p)[64 + lane] = o1;
}

// -----------------------------------------------------------------------------
extern "C" void kernel_launch(void* const* d_in, const int* in_sizes, int n_in,
                              void* d_out, int out_size, void* d_ws, size_t ws_size,
                              hipStream_t stream) {
  (void)in_sizes; (void)n_in; (void)out_size;
  const float* x  = (const float*)d_in[0];
  const float* y  = (const float*)d_in[1];
  const float* wq = (const float*)d_in[2];
  const float* bq = (const float*)d_in[3];
  const float* wk = (const float*)d_in[4];
  const float* bk = (const float*)d_in[5];
  const float* wv = (const float*)d_in[6];
  const float* bv = (const float*)d_in[7];

  char* ws = (char*)d_ws;
  size_t off = 0;
  auto alloc = [&](size_t bytes) {
    void* p = ws + off;
    off = (off + bytes + 255) & ~(size_t)255;
    return p;
  };
  const size_t act_b = (size_t)BATCH * NTOK * CCH * 2;  // 16 MB
  f16_t* x_t    = (f16_t*)alloc(act_b);
  f16_t* y_t    = (f16_t*)alloc(act_b);
  f16_t* wcat   = (f16_t*)alloc((size_t)27 * 3072 * 1024 * 2);   // 170 MB
  float* bcat   = (float*)alloc(3072 * 4);
  f16_t* qb     = (f16_t*)alloc(act_b);
  f16_t* kb     = (f16_t*)alloc(act_b);
  f16_t* vb     = (f16_t*)alloc(act_b);
  float* scores = (float*)alloc((size_t)BATCH * 512 * 512 * 4);  // 16 MB
  f16_t* Pb     = (f16_t*)alloc((size_t)BATCH * 512 * 512 * 2);  //  8 MB
  char*  zerop  = (char*)alloc(4096);
  if (off > ws_size) return;

  const dim3 blk(256);
  hipMemsetAsync(zerop, 0, 4096, stream);
  cast_transpose_kernel<<<dim3(8, 16, 16), blk, 0, stream>>>(x, x_t);
  cast_transpose_kernel<<<dim3(8, 16, 16), blk, 0, stream>>>(y, y_t);

  wtrans_kernel<<<dim3(1024, 16), blk, 0, stream>>>(wq, wcat, 0);
  wtrans_kernel<<<dim3(1024, 16), blk, 0, stream>>>(wk, wcat, 1024);
  wtrans_kernel<<<dim3(1024, 16), blk, 0, stream>>>(wv, wcat, 2048);
  hipMemcpyAsync(bcat,        bq, 1024 * 4, hipMemcpyDeviceToDevice, stream);
  hipMemcpyAsync(bcat + 1024, bk, 1024 * 4, hipMemcpyDeviceToDevice, stream);
  hipMemcpyAsync(bcat + 2048, bv, 1024 * 4, hipMemcpyDeviceToDevice, stream);

  conv_fused_kernel<<<dim3(768), dim3(512), 0, stream>>>(
      x_t, y_t, wcat, bcat, qb, kb, vb, zerop);

  // scores[b][n][m] = sum_c q[b][n][c] * k[b][m][c]
  attn_gemm_kernel<<<dim3(4, 4, 16), blk, 0, stream>>>(
      qb, kb, scores, nullptr, 1024, 512,
      (size_t)512 * 1024, (size_t)512 * 1024, (size_t)512 * 512);
  softmax_kernel<<<dim3(BATCH * 512 / 4), blk, 0, stream>>>(scores, Pb);
  // out[b][c][n] = sum_m v[b][c][m] * P[b][n][m] + x[b][c][n]
  attn_gemm_kernel<<<dim3(4, 8, 16), blk, 0, stream>>>(
      vb, Pb, (float*)d_out, x, 512, 512,
      (size_t)1024 * 512, (size_t)512 * 512, (size_t)1024 * 512);
}

// Round 5
// 1513.731 us; speedup vs baseline: 1.0624x; 1.0624x over previous
//
#include <hip/hip_runtime.h>
#include <hip/hip_bf16.h>
#include <stdint.h>

// B=16, C=1024, D=H=W=8 -> N=512 tokens, 27 taps
#define BATCH 16
#define CCH   1024
#define NTOK  512
#define NKT   432   // K-tiles: 27 taps * (1024/64)

typedef _Float16 f16_t;
typedef f16_t f16x8 __attribute__((ext_vector_type(8)));
typedef f16_t f16x4 __attribute__((ext_vector_type(4)));
typedef float f32x4 __attribute__((ext_vector_type(4)));

#define GAS __attribute__((address_space(1)))
#define LAS __attribute__((address_space(3)))

__device__ __forceinline__ void gload_lds16(const void* g, void* l) {
  __builtin_amdgcn_global_load_lds((const GAS uint32_t*)g, (LAS uint32_t*)l, 16, 0, 0);
}

// ---------------- cast + transpose: [B][C][N] f32 -> [B][N][C] f16 -----------
__global__ __launch_bounds__(256) void cast_transpose_kernel(
    const float* __restrict__ src, f16_t* __restrict__ dst) {
  __shared__ float tile[64][65];
  const int b  = blockIdx.z;
  const int c0 = blockIdx.y * 64;
  const int n0 = blockIdx.x * 64;
  const int col  = threadIdx.x & 63;
  const int row4 = threadIdx.x >> 6;
  const float* s = src + ((size_t)b * CCH + c0) * NTOK + n0;
#pragma unroll
  for (int r = 0; r < 64; r += 4)
    tile[r + row4][col] = s[(size_t)(r + row4) * NTOK + col];
  __syncthreads();
  f16_t* d = dst + ((size_t)b * NTOK + n0) * CCH + c0;
#pragma unroll
  for (int r = 0; r < 64; r += 4)
    d[(size_t)(r + row4) * CCH + col] = (f16_t)tile[col][r + row4];
}

// -------- weight transpose: [O][I][27] f32 -> rows o_base+o of [27][Mtot][1024]
__global__ __launch_bounds__(256) void wtrans_kernel(
    const float* __restrict__ w, f16_t* __restrict__ wt, const int o_base,
    const int Mtot) {
  __shared__ float buf[64 * 27];
  const int o  = blockIdx.x;
  const int i0 = blockIdx.y * 64;
  const float* s = w + (size_t)o * (CCH * 27) + (size_t)i0 * 27;
  for (int idx = threadIdx.x; idx < 64 * 27; idx += 256) buf[idx] = s[idx];
  __syncthreads();
  for (int idx = threadIdx.x; idx < 64 * 27; idx += 256) {
    const int t = idx >> 6;
    const int i = idx & 63;
    wt[((size_t)t * Mtot + o_base + o) * 1024 + i0 + i] = (f16_t)buf[i * 27 + t];
  }
}

// ================= conv K+V fused: M=2048, tile 256x256, BK=64 ===============
// 256 blocks (8 m-panels x 32 n-tiles), 512 thr = 8 waves (2M x 4N),
// wave tile 128x64, acc 8x4. True double-buffer (2 x 64KB): one barrier +
// vmcnt(0) per K-tile; stage for t+1 issued at tile top -> latency covered by
// ~2400cyc of MFMA. Swizzle: 16B slot s of each 64B k-half stored at
// s ^ ((row>>1)&3) via pre-swizzled global source; same XOR on ds_read.
__global__ __launch_bounds__(512, 2) void conv_kv_kernel(
    const f16_t* __restrict__ y_t, const f16_t* __restrict__ wkv,
    const float* __restrict__ bkv, f16_t* __restrict__ kb,
    f16_t* __restrict__ vb, const char* __restrict__ zp) {
  __shared__ char lds[131072];
  const int tid  = threadIdx.x;
  const int lane = tid & 63;
  const int wid  = tid >> 6;
  const int wr = wid >> 2, wc = wid & 3;   // 2M x 4N

  const int id = blockIdx.x;               // 256 blocks, panel == id&7 -> XCD
  const int panel  = id & 7;               // 0..7 (0-3 = k, 4-7 = v)
  const int n_tile = id >> 3;              // 0..31
  const int m0  = panel * 256;             // row in 2048
  const int bn0 = n_tile * 256;
  const int b   = bn0 >> 9;
  const int n0  = bn0 & 511;
  const char* src_c = (const char*)y_t + (size_t)b * NTOK * 2048;
  const char* w_c   = (const char*)wkv;

  const int slotsrc16 = (((tid & 3) ^ ((tid >> 3) & 3)) << 4);
  const int t16 = tid << 4;
  const int r0  = tid >> 2;                // 0..127
  const size_t arow0 = (size_t)(m0 + r0) * 2048 + slotsrc16;

  int cur_tap = -1;
  const char* bp0 = zp;
  const char* bp1 = zp;

  const int fr = lane & 15;
  const int rdbase = fr * 64 + (((lane >> 4) ^ ((fr >> 1) & 3)) << 4);

  f32x4 acc[8][4] = {};

  auto upd_tap = [&](int tap) {
    cur_tap = tap;
    const int kd = tap / 9, rem = tap % 9, kh = rem / 3, kw = rem % 3;
#pragma unroll
    for (int l = 0; l < 2; ++l) {
      const int n = n0 + r0 + l * 128;
      const int d = (n >> 6) + kd - 1;
      const int h = ((n >> 3) & 7) + kh - 1;
      const int w = (n & 7) + kw - 1;
      const bool ok = ((unsigned)d < 8u) & ((unsigned)h < 8u) & ((unsigned)w < 8u);
      const int nsrc = (d << 6) + (h << 3) + w;
      const char* p = ok ? src_c + (size_t)nsrc * 2048 + slotsrc16 : zp;
      if (l == 0) bp0 = p; else bp1 = p;
    }
  };
  auto stage = [&](int tt, int setb) {     // 8 issues, uniform across waves
    const int tap = tt >> 4, kt = tt & 15;
    if (tap != cur_tap) upd_tap(tap);
    const size_t gA = (size_t)tap * (2048u * 2048u) + (size_t)kt * 128;
    char* La = lds + setb;
    gload_lds16(w_c + gA + arow0,                        La + t16);          // A kh0 rows 0-127
    gload_lds16(w_c + gA + arow0 + (size_t)128 * 2048,   La + 8192 + t16);   // A kh0 rows 128-255
    gload_lds16(w_c + gA + 64 + arow0,                   La + 16384 + t16);  // A kh1 rows 0-127
    gload_lds16(w_c + gA + 64 + arow0 + (size_t)128*2048,La + 24576 + t16);  // A kh1 rows 128-255
    const int gB = kt * 128;
    gload_lds16(bp0 + gB,      La + 32768 + t16);        // B kh0 rows 0-127
    gload_lds16(bp1 + gB,      La + 40960 + t16);        // B kh0 rows 128-255
    gload_lds16(bp0 + gB + 64, La + 49152 + t16);        // B kh1 rows 0-127
    gload_lds16(bp1 + gB + 64, La + 57344 + t16);        // B kh1 rows 128-255
  };

  stage(0, 0);
  asm volatile("s_waitcnt vmcnt(0)\n\ts_barrier" ::: "memory");

#pragma unroll 1
  for (int t = 0; t < NKT; ++t) {
    const int setb = (t & 1) << 16;
    if (t + 1 < NKT) stage(t + 1, ((t + 1) & 1) << 16);
#pragma unroll
    for (int kh = 0; kh < 2; ++kh) {
      const char* sA = lds + setb + kh * 16384 + wr * 8192 + rdbase;
      const char* sB = lds + setb + 32768 + kh * 16384 + wc * 4096 + rdbase;
      f16x8 bv[4];
#pragma unroll
      for (int j = 0; j < 4; ++j) bv[j] = *(const f16x8*)(sB + j * 1024);
#pragma unroll
      for (int i2 = 0; i2 < 2; ++i2) {
        f16x8 av[4];
#pragma unroll
        for (int i = 0; i < 4; ++i) av[i] = *(const f16x8*)(sA + (i2 * 4 + i) * 1024);
#pragma unroll
        for (int i = 0; i < 4; ++i)
#pragma unroll
          for (int j = 0; j < 4; ++j)
            acc[i2 * 4 + i][j] = __builtin_amdgcn_mfma_f32_16x16x32_f16(
                av[i], bv[j], acc[i2 * 4 + i][j], 0, 0, 0);
      }
    }
    asm volatile("s_waitcnt vmcnt(0)\n\ts_barrier" ::: "memory");
  }

  // epilogue
  const int rq = (lane >> 4) << 2;
  const bool is_k = panel < 4;
#pragma unroll
  for (int i = 0; i < 8; ++i) {
    const int c = m0 + wr * 128 + i * 16 + rq;       // 0..2047
    const float4 bs = *(const float4*)&bkv[c];
    if (is_k) {
#pragma unroll
      for (int j = 0; j < 4; ++j) {
        const int n = n0 + wc * 64 + j * 16 + fr;
        f16x4 pk;
        pk[0] = (f16_t)(acc[i][j][0] + bs.x);
        pk[1] = (f16_t)(acc[i][j][1] + bs.y);
        pk[2] = (f16_t)(acc[i][j][2] + bs.z);
        pk[3] = (f16_t)(acc[i][j][3] + bs.w);
        *(f16x4*)(kb + ((size_t)(b * NTOK + n)) * CCH + c) = pk;
      }
    } else {
      const int cc = c - 1024;
      const float bb[4] = {bs.x, bs.y, bs.z, bs.w};
#pragma unroll
      for (int reg = 0; reg < 4; ++reg) {
        f16_t* dst = vb + ((size_t)b * CCH + cc + reg) * NTOK;
#pragma unroll
        for (int j = 0; j < 4; ++j) {
          const int n = n0 + wc * 64 + j * 16 + fr;
          dst[n] = (f16_t)(acc[i][j][reg] + bb[reg]);
        }
      }
    }
  }
}

// ================= conv Q: M=1024, tile 256x128, BK=64 =======================
// 256 blocks (4 m-panels x 64 n-tiles), 512 thr = 8 waves (4M x 2N),
// wave tile 64x64, acc 4x4. Double-buffer 2 x 48KB, 6 issues/tile.
__global__ __launch_bounds__(512, 2) void conv_q_kernel(
    const f16_t* __restrict__ x_t, const f16_t* __restrict__ wqt,
    const float* __restrict__ bq, f16_t* __restrict__ qb,
    const char* __restrict__ zp) {
  __shared__ char lds[98304];
  const int tid  = threadIdx.x;
  const int lane = tid & 63;
  const int wid  = tid >> 6;
  const int wr = wid >> 1, wc = wid & 1;   // 4M x 2N

  const int id = blockIdx.x;               // 256 blocks
  const int panel  = id & 3;               // 0..3
  const int n_tile = id >> 2;              // 0..63
  const int m0  = panel * 256;
  const int bn0 = n_tile * 128;
  const int b   = bn0 >> 9;
  const int n0  = bn0 & 511;
  const char* src_c = (const char*)x_t + (size_t)b * NTOK * 2048;
  const char* w_c   = (const char*)wqt;

  const int slotsrc16 = (((tid & 3) ^ ((tid >> 3) & 3)) << 4);
  const int t16 = tid << 4;
  const int r0  = tid >> 2;                // 0..127
  const size_t arow0 = (size_t)(m0 + r0) * 2048 + slotsrc16;

  int cur_tap = -1;
  const char* bp0 = zp;

  const int fr = lane & 15;
  const int rdbase = fr * 64 + (((lane >> 4) ^ ((fr >> 1) & 3)) << 4);

  f32x4 acc[4][4] = {};

  auto upd_tap = [&](int tap) {
    cur_tap = tap;
    const int kd = tap / 9, rem = tap % 9, kh = rem / 3, kw = rem % 3;
    const int n = n0 + r0;
    const int d = (n >> 6) + kd - 1;
    const int h = ((n >> 3) & 7) + kh - 1;
    const int w = (n & 7) + kw - 1;
    const bool ok = ((unsigned)d < 8u) & ((unsigned)h < 8u) & ((unsigned)w < 8u);
    const int nsrc = (d << 6) + (h << 3) + w;
    bp0 = ok ? src_c + (size_t)nsrc * 2048 + slotsrc16 : zp;
  };
  auto stage = [&](int tt, int setb) {     // 6 issues, uniform
    const int tap = tt >> 4, kt = tt & 15;
    if (tap != cur_tap) upd_tap(tap);
    const size_t gA = (size_t)tap * (1024u * 2048u) + (size_t)kt * 128;
    char* La = lds + setb;
    gload_lds16(w_c + gA + arow0,                         La + t16);
    gload_lds16(w_c + gA + arow0 + (size_t)128 * 2048,    La + 8192 + t16);
    gload_lds16(w_c + gA + 64 + arow0,                    La + 16384 + t16);
    gload_lds16(w_c + gA + 64 + arow0 + (size_t)128*2048, La + 24576 + t16);
    const int gB = kt * 128;
    gload_lds16(bp0 + gB,      La + 32768 + t16);        // B kh0 (128 rows)
    gload_lds16(bp0 + gB + 64, La + 40960 + t16);        // B kh1
  };

  stage(0, 0);
  asm volatile("s_waitcnt vmcnt(0)\n\ts_barrier" ::: "memory");

#pragma unroll 1
  for (int t = 0; t < NKT; ++t) {
    const int setb = (t & 1) * 49152;
    if (t + 1 < NKT) stage(t + 1, ((t + 1) & 1) * 49152);
#pragma unroll
    for (int kh = 0; kh < 2; ++kh) {
      const char* sA = lds + setb + kh * 16384 + wr * 4096 + rdbase;
      const char* sB = lds + setb + 32768 + kh * 8192 + wc * 4096 + rdbase;
      f16x8 av[4], bv[4];
#pragma unroll
      for (int j = 0; j < 4; ++j) bv[j] = *(const f16x8*)(sB + j * 1024);
#pragma unroll
      for (int i = 0; i < 4; ++i) av[i] = *(const f16x8*)(sA + i * 1024);
#pragma unroll
      for (int i = 0; i < 4; ++i)
#pragma unroll
        for (int j = 0; j < 4; ++j)
          acc[i][j] = __builtin_amdgcn_mfma_f32_16x16x32_f16(av[i], bv[j], acc[i][j], 0, 0, 0);
    }
    asm volatile("s_waitcnt vmcnt(0)\n\ts_barrier" ::: "memory");
  }

  const int rq = (lane >> 4) << 2;
#pragma unroll
  for (int i = 0; i < 4; ++i) {
    const int c = m0 + wr * 64 + i * 16 + rq;        // 0..1023
    const float4 bs = *(const float4*)&bq[c];
#pragma unroll
    for (int j = 0; j < 4; ++j) {
      const int n = n0 + wc * 64 + j * 16 + fr;
      f16x4 pk;
      pk[0] = (f16_t)(acc[i][j][0] + bs.x);
      pk[1] = (f16_t)(acc[i][j][1] + bs.y);
      pk[2] = (f16_t)(acc[i][j][2] + bs.z);
      pk[3] = (f16_t)(acc[i][j][3] + bs.w);
      *(f16x4*)(qb + ((size_t)(b * NTOK + n)) * CCH + c) = pk;
    }
  }
}

// ---------------- generic gemm_bt for attention: C = A * Bt^T (+resid) -------
__global__ __launch_bounds__(256) void attn_gemm_kernel(
    const f16_t* __restrict__ A, const f16_t* __restrict__ Bt,
    float* __restrict__ Cout, const float* __restrict__ resid,
    const int Kdim, const int ldc,
    const size_t strideA, const size_t strideB, const size_t strideC) {
  __shared__ f16_t As[128 * 64];
  __shared__ f16_t Bs[128 * 64];
  char* As_c = (char*)As;
  char* Bs_c = (char*)Bs;

  const int tid  = threadIdx.x;
  const int lane = tid & 63;
  const int wave = tid >> 6;
  const int wr = wave >> 1, wc = wave & 1;
  const int bz = blockIdx.z;
  const int m0 = blockIdx.y * 128;
  const int n0 = blockIdx.x * 128;

  const f16_t* Ab = A + (size_t)bz * strideA;
  const f16_t* Bb = Bt + (size_t)bz * strideB;

  const int rowb = tid >> 3;
  const int colb = (tid & 7) * 16;

  const char* ap[4];
  const char* bp[4];
#pragma unroll
  for (int r = 0; r < 4; ++r) {
    const int row = r * 32 + rowb;
    ap[r] = (const char*)(Ab + (size_t)(m0 + row) * Kdim) + colb;
    bp[r] = (const char*)(Bb + (size_t)(n0 + row) * Kdim) + colb;
  }

  f32x4 acc[4][4] = {};
  const int fr = lane & 15;
  const int fk = (lane >> 4) << 3;

  for (int k0 = 0; k0 < Kdim; k0 += 64) {
#pragma unroll
    for (int r = 0; r < 4; ++r)
      gload_lds16(ap[r], As_c + r * 4096 + wave * 1024);
#pragma unroll
    for (int r = 0; r < 4; ++r)
      gload_lds16(bp[r], Bs_c + r * 4096 + wave * 1024);
#pragma unroll
    for (int r = 0; r < 4; ++r) { ap[r] += 128; bp[r] += 128; }
    __syncthreads();
#pragma unroll
    for (int ks = 0; ks < 2; ++ks) {
      const int kc = ks * 32 + fk;
      f16x8 av[4], bv[4];
#pragma unroll
      for (int i = 0; i < 4; ++i)
        av[i] = *(const f16x8*)&As[(wr * 64 + i * 16 + fr) * 64 + kc];
#pragma unroll
      for (int i = 0; i < 4; ++i)
        bv[i] = *(const f16x8*)&Bs[(wc * 64 + i * 16 + fr) * 64 + kc];
#pragma unroll
      for (int i = 0; i < 4; ++i)
#pragma unroll
        for (int j = 0; j < 4; ++j)
          acc[i][j] = __builtin_amdgcn_mfma_f32_16x16x32_f16(av[i], bv[j], acc[i][j], 0, 0, 0);
    }
    __syncthreads();
  }

  const int mo = m0 + wr * 64 + ((lane >> 4) << 2);
  const int nn = n0 + wc * 64 + (lane & 15);
  float* Cb = Cout + (size_t)bz * strideC;
  const float* Rb = resid ? resid + (size_t)bz * strideC : nullptr;
#pragma unroll
  for (int i = 0; i < 4; ++i) {
#pragma unroll
    for (int j = 0; j < 4; ++j) {
      const int n = nn + j * 16;
#pragma unroll
      for (int reg = 0; reg < 4; ++reg) {
        const int m = mo + i * 16 + reg;
        float v = acc[i][j][reg];
        if (Rb) v += Rb[(size_t)m * ldc + n];
        Cb[(size_t)m * ldc + n] = v;
      }
    }
  }
}

// ---------------- row softmax: S fp32 [rows][512] -> P f16 -------------------
__global__ __launch_bounds__(256) void softmax_kernel(
    const float* __restrict__ S, f16_t* __restrict__ P) {
  const int row  = blockIdx.x * 4 + (threadIdx.x >> 6);
  const int lane = threadIdx.x & 63;
  const float* s = S + (size_t)row * 512;
  const float4 v0 = ((const float4*)s)[lane];
  const float4 v1 = ((const float4*)s)[64 + lane];
  float m = fmaxf(fmaxf(fmaxf(v0.x, v0.y), fmaxf(v0.z, v0.w)),
                  fmaxf(fmaxf(v1.x, v1.y), fmaxf(v1.z, v1.w)));
#pragma unroll
  for (int o = 32; o; o >>= 1) m = fmaxf(m, __shfl_xor(m, o, 64));
  float e[8];
  e[0] = __expf(v0.x - m); e[1] = __expf(v0.y - m);
  e[2] = __expf(v0.z - m); e[3] = __expf(v0.w - m);
  e[4] = __expf(v1.x - m); e[5] = __expf(v1.y - m);
  e[6] = __expf(v1.z - m); e[7] = __expf(v1.w - m);
  float sum = ((e[0] + e[1]) + (e[2] + e[3])) + ((e[4] + e[5]) + (e[6] + e[7]));
#pragma unroll
  for (int o = 32; o; o >>= 1) sum += __shfl_xor(sum, o, 64);
  const float r = 1.0f / sum;
  f16_t* p = P + (size_t)row * 512;
  f16x4 o0, o1;
  o0[0] = (f16_t)(e[0] * r); o0[1] = (f16_t)(e[1] * r);
  o0[2] = (f16_t)(e[2] * r); o0[3] = (f16_t)(e[3] * r);
  o1[0] = (f16_t)(e[4] * r); o1[1] = (f16_t)(e[5] * r);
  o1[2] = (f16_t)(e[6] * r); o1[3] = (f16_t)(e[7] * r);
  ((f16x4*)p)[lane] = o0;
  ((f16x4*)p)[64 + lane] = o1;
}

// -----------------------------------------------------------------------------
extern "C" void kernel_launch(void* const* d_in, const int* in_sizes, int n_in,
                              void* d_out, int out_size, void* d_ws, size_t ws_size,
                              hipStream_t stream) {
  (void)in_sizes; (void)n_in; (void)out_size;
  const float* x  = (const float*)d_in[0];
  const float* y  = (const float*)d_in[1];
  const float* wq = (const float*)d_in[2];
  const float* bq = (const float*)d_in[3];
  const float* wk = (const float*)d_in[4];
  const float* bk = (const float*)d_in[5];
  const float* wv = (const float*)d_in[6];
  const float* bv = (const float*)d_in[7];

  char* ws = (char*)d_ws;
  size_t off = 0;
  auto alloc = [&](size_t bytes) {
    void* p = ws + off;
    off = (off + bytes + 255) & ~(size_t)255;
    return p;
  };
  const size_t act_b = (size_t)BATCH * NTOK * CCH * 2;  // 16 MB
  f16_t* x_t    = (f16_t*)alloc(act_b);
  f16_t* y_t    = (f16_t*)alloc(act_b);
  f16_t* wkv    = (f16_t*)alloc((size_t)27 * 2048 * 1024 * 2);   // 113 MB
  f16_t* wqt    = (f16_t*)alloc((size_t)27 * 1024 * 1024 * 2);   //  57 MB
  float* bkv    = (float*)alloc(2048 * 4);
  f16_t* qb     = (f16_t*)alloc(act_b);
  f16_t* kb     = (f16_t*)alloc(act_b);
  f16_t* vb     = (f16_t*)alloc(act_b);
  float* scores = (float*)alloc((size_t)BATCH * 512 * 512 * 4);  // 16 MB
  f16_t* Pb     = (f16_t*)alloc((size_t)BATCH * 512 * 512 * 2);  //  8 MB
  char*  zerop  = (char*)alloc(4096);
  if (off > ws_size) return;

  const dim3 blk(256);
  hipMemsetAsync(zerop, 0, 4096, stream);
  cast_transpose_kernel<<<dim3(8, 16, 16), blk, 0, stream>>>(x, x_t);
  cast_transpose_kernel<<<dim3(8, 16, 16), blk, 0, stream>>>(y, y_t);

  wtrans_kernel<<<dim3(1024, 16), blk, 0, stream>>>(wk, wkv, 0, 2048);
  wtrans_kernel<<<dim3(1024, 16), blk, 0, stream>>>(wv, wkv, 1024, 2048);
  wtrans_kernel<<<dim3(1024, 16), blk, 0, stream>>>(wq, wqt, 0, 1024);
  hipMemcpyAsync(bkv,        bk, 1024 * 4, hipMemcpyDeviceToDevice, stream);
  hipMemcpyAsync(bkv + 1024, bv, 1024 * 4, hipMemcpyDeviceToDevice, stream);

  conv_kv_kernel<<<dim3(256), dim3(512), 0, stream>>>(y_t, wkv, bkv, kb, vb, zerop);
  conv_q_kernel<<<dim3(256), dim3(512), 0, stream>>>(x_t, wqt, bq, qb, zerop);

  // scores[b][n][m] = sum_c q[b][n][c] * k[b][m][c]
  attn_gemm_kernel<<<dim3(4, 4, 16), blk, 0, stream>>>(
      qb, kb, scores, nullptr, 1024, 512,
      (size_t)512 * 1024, (size_t)512 * 1024, (size_t)512 * 512);
  softmax_kernel<<<dim3(BATCH * 512 / 4), blk, 0, stream>>>(scores, Pb);
  // out[b][c][n] = sum_m v[b][c][m] * P[b][n][m] + x[b][c][n]
  attn_gemm_kernel<<<dim3(4, 8, 16), blk, 0, stream>>>(
      vb, Pb, (float*)d_out, x, 512, 512,
      (size_t)1024 * 512, (size_t)512 * 512, (size_t)1024 * 512);
}

// Round 6
// 1406.691 us; speedup vs baseline: 1.1432x; 1.0761x over previous
//
#include <hip/hip_runtime.h>
#include <hip/hip_bf16.h>
#include <stdint.h>

// B=16, C=1024, D=H=W=8 -> N=512 tokens, 27 taps
#define BATCH 16
#define CCH   1024
#define NTOK  512
#define NKT   432   // K-tiles: 27 taps * (1024/64)

typedef _Float16 f16_t;
typedef f16_t f16x8 __attribute__((ext_vector_type(8)));
typedef f16_t f16x4 __attribute__((ext_vector_type(4)));
typedef float f32x4 __attribute__((ext_vector_type(4)));

#define GAS __attribute__((address_space(1)))
#define LAS __attribute__((address_space(3)))

__device__ __forceinline__ void gload_lds16(const void* g, void* l) {
  __builtin_amdgcn_global_load_lds((const GAS uint32_t*)g, (LAS uint32_t*)l, 16, 0, 0);
}

// ---------------- cast + transpose: [B][C][N] f32 -> [B][N][C] f16 -----------
__global__ __launch_bounds__(256) void cast_transpose_kernel(
    const float* __restrict__ src, f16_t* __restrict__ dst) {
  __shared__ float tile[64][65];
  const int b  = blockIdx.z;
  const int c0 = blockIdx.y * 64;
  const int n0 = blockIdx.x * 64;
  const int col  = threadIdx.x & 63;
  const int row4 = threadIdx.x >> 6;
  const float* s = src + ((size_t)b * CCH + c0) * NTOK + n0;
#pragma unroll
  for (int r = 0; r < 64; r += 4)
    tile[r + row4][col] = s[(size_t)(r + row4) * NTOK + col];
  __syncthreads();
  f16_t* d = dst + ((size_t)b * NTOK + n0) * CCH + c0;
#pragma unroll
  for (int r = 0; r < 64; r += 4)
    d[(size_t)(r + row4) * CCH + col] = (f16_t)tile[col][r + row4];
}

// -------- weight transpose: [O][I][27] f32 -> rows o_base+o of [27][Mtot][1024]
__global__ __launch_bounds__(256) void wtrans_kernel(
    const float* __restrict__ w, f16_t* __restrict__ wt, const int o_base,
    const int Mtot) {
  __shared__ float buf[64 * 27];
  const int o  = blockIdx.x;
  const int i0 = blockIdx.y * 64;
  const float* s = w + (size_t)o * (CCH * 27) + (size_t)i0 * 27;
  for (int idx = threadIdx.x; idx < 64 * 27; idx += 256) buf[idx] = s[idx];
  __syncthreads();
  for (int idx = threadIdx.x; idx < 64 * 27; idx += 256) {
    const int t = idx >> 6;
    const int i = idx & 63;
    wt[((size_t)t * Mtot + o_base + o) * 1024 + i0 + i] = (f16_t)buf[i * 27 + t];
  }
}

// ================= conv K+V fused: M=2048, tile 256x256, BK=64 ===============
// 256 blocks (8 m-panels x 32 n-tiles), 512 thr = 8 waves (2M x 4N),
// wave tile 128x64, acc 8x4. K-tile split into 2 kh-halves of 32KB
// (A 16K + B 16K); 4-half ring (128KB). Per phase: vmcnt(8)+barrier ->
// ds_read 12 frags -> stage half h+3 (4 loads) -> setprio+32 MFMA.
// Counted vmcnt(8) keeps 2 halves (8 loads) in flight across every barrier;
// issue-to-wait ~3 phases covers HBM latency. Tail: source remap te->te-2.
__global__ __launch_bounds__(512, 2) void conv_kv_kernel(
    const f16_t* __restrict__ y_t, const f16_t* __restrict__ wkv,
    const float* __restrict__ bkv, f16_t* __restrict__ kb,
    f16_t* __restrict__ vb, const char* __restrict__ zp) {
  __shared__ char lds[131072];
  const int tid  = threadIdx.x;
  const int lane = tid & 63;
  const int wid  = tid >> 6;
  const int wr = wid >> 2, wc = wid & 3;   // 2M x 4N

  const int id = blockIdx.x;               // 256 blocks, panel == id&7 -> XCD
  const int panel  = id & 7;               // 0..7 (0-3 = k, 4-7 = v)
  const int n_tile = id >> 3;              // 0..31
  const int m0  = panel * 256;             // row in 2048
  const int bn0 = n_tile * 256;
  const int b   = bn0 >> 9;
  const int n0  = bn0 & 511;
  const char* src_c = (const char*)y_t + (size_t)b * NTOK * 2048;
  const char* w_c   = (const char*)wkv;

  const int slotsrc16 = (((tid & 3) ^ ((tid >> 3) & 3)) << 4);
  const int t16 = tid << 4;
  const int r0  = tid >> 2;                // 0..127
  const size_t arow0 = (size_t)(m0 + r0) * 2048 + slotsrc16;

  int cur_tap = -1;
  const char* bp0 = zp;
  const char* bp1 = zp;

  const int fr = lane & 15;
  const int rdbase = fr * 64 + (((lane >> 4) ^ ((fr >> 1) & 3)) << 4);

  f32x4 acc[8][4] = {};

  auto upd_tap = [&](int tap) {
    cur_tap = tap;
    const int kd = tap / 9, rem = tap % 9, kh = rem / 3, kw = rem % 3;
#pragma unroll
    for (int l = 0; l < 2; ++l) {
      const int n = n0 + r0 + l * 128;
      const int d = (n >> 6) + kd - 1;
      const int h = ((n >> 3) & 7) + kh - 1;
      const int w = (n & 7) + kw - 1;
      const bool ok = ((unsigned)d < 8u) & ((unsigned)h < 8u) & ((unsigned)w < 8u);
      const int nsrc = (d << 6) + (h << 3) + w;
      const char* p = ok ? src_c + (size_t)nsrc * 2048 + slotsrc16 : zp;
      if (l == 0) bp0 = p; else bp1 = p;
    }
  };
  // stage one kh-half (4 loads) of K-tile tt into ring region `reg`
  auto stage_half = [&](int tt, int kh, int reg) {
    const int te = (tt < NKT) ? tt : tt - 2;   // tail remap, counts stay exact
    const int tap = te >> 4, kt = te & 15;
    if (tap != cur_tap) upd_tap(tap);
    const size_t gA = (size_t)tap * (2048u * 2048u) + (size_t)(kt * 128 + kh * 64);
    char* La = lds + reg;
    gload_lds16(w_c + gA + arow0,                      La + t16);          // A rows 0-127
    gload_lds16(w_c + gA + arow0 + (size_t)128 * 2048, La + 8192 + t16);   // A rows 128-255
    const int gB = kt * 128 + kh * 64;
    gload_lds16(bp0 + gB, La + 16384 + t16);                               // B rows 0-127
    gload_lds16(bp1 + gB, La + 24576 + t16);                               // B rows 128-255
  };

#define MFMA32(AV, BV)                                                         \
  _Pragma("unroll") for (int i = 0; i < 8; ++i) {                              \
    _Pragma("unroll") for (int j = 0; j < 4; ++j)                              \
        acc[i][j] = __builtin_amdgcn_mfma_f32_16x16x32_f16(                    \
            AV[i], BV[j], acc[i][j], 0, 0, 0);                                 \
  }

  // prologue: halves (0,0)(0,1)(1,0) = 12 loads; wait half0 (keep 8 in flight)
  stage_half(0, 0, 0);
  stage_half(0, 1, 32768);
  stage_half(1, 0, 65536);
  asm volatile("s_waitcnt vmcnt(8)\n\ts_barrier" ::: "memory");

#pragma unroll 1
  for (int t = 0; t < NKT; ++t) {
    const int rb = (t & 1) << 16;                 // region: tile t, kh0
    // ---- phase kh0
    {
      const char* sA = lds + rb + wr * 8192 + rdbase;
      const char* sB = lds + rb + 16384 + wc * 4096 + rdbase;
      f16x8 av[8], bv[4];
#pragma unroll
      for (int j = 0; j < 4; ++j) bv[j] = *(const f16x8*)(sB + j * 1024);
#pragma unroll
      for (int i = 0; i < 8; ++i) av[i] = *(const f16x8*)(sA + i * 1024);
      stage_half(t + 1, 1, (((t + 1) & 1) << 16) + 32768);
      __builtin_amdgcn_s_setprio(1);
      MFMA32(av, bv)
      __builtin_amdgcn_s_setprio(0);
      asm volatile("s_waitcnt vmcnt(8)\n\ts_barrier" ::: "memory");
    }
    // ---- phase kh1
    {
      const char* sA = lds + rb + 32768 + wr * 8192 + rdbase;
      const char* sB = lds + rb + 32768 + 16384 + wc * 4096 + rdbase;
      f16x8 av[8], bv[4];
#pragma unroll
      for (int j = 0; j < 4; ++j) bv[j] = *(const f16x8*)(sB + j * 1024);
#pragma unroll
      for (int i = 0; i < 8; ++i) av[i] = *(const f16x8*)(sA + i * 1024);
      stage_half(t + 2, 0, (t & 1) << 16);
      __builtin_amdgcn_s_setprio(1);
      MFMA32(av, bv)
      __builtin_amdgcn_s_setprio(0);
      asm volatile("s_waitcnt vmcnt(8)\n\ts_barrier" ::: "memory");
    }
  }
#undef MFMA32

  // epilogue
  const int rq = (lane >> 4) << 2;
  const bool is_k = panel < 4;
#pragma unroll
  for (int i = 0; i < 8; ++i) {
    const int c = m0 + wr * 128 + i * 16 + rq;       // 0..2047
    const float4 bs = *(const float4*)&bkv[c];
    if (is_k) {
#pragma unroll
      for (int j = 0; j < 4; ++j) {
        const int n = n0 + wc * 64 + j * 16 + fr;
        f16x4 pk;
        pk[0] = (f16_t)(acc[i][j][0] + bs.x);
        pk[1] = (f16_t)(acc[i][j][1] + bs.y);
        pk[2] = (f16_t)(acc[i][j][2] + bs.z);
        pk[3] = (f16_t)(acc[i][j][3] + bs.w);
        *(f16x4*)(kb + ((size_t)(b * NTOK + n)) * CCH + c) = pk;
      }
    } else {
      const int cc = c - 1024;
      const float bb[4] = {bs.x, bs.y, bs.z, bs.w};
#pragma unroll
      for (int reg = 0; reg < 4; ++reg) {
        f16_t* dst = vb + ((size_t)b * CCH + cc + reg) * NTOK;
#pragma unroll
        for (int j = 0; j < 4; ++j) {
          const int n = n0 + wc * 64 + j * 16 + fr;
          dst[n] = (f16_t)(acc[i][j][reg] + bb[reg]);
        }
      }
    }
  }
}

// ================= conv Q: M=1024, tile 256x128, BK=64 =======================
// 256 blocks (4 m-panels x 64 n-tiles), 8 waves (4M x 2N), wave 64x64,
// acc 4x4. kh-half = 24KB (A 16K + B 8K), 4-half ring (96KB), 3 loads/half,
// counted vmcnt(6). Same phase structure as conv_kv.
__global__ __launch_bounds__(512, 2) void conv_q_kernel(
    const f16_t* __restrict__ x_t, const f16_t* __restrict__ wqt,
    const float* __restrict__ bq, f16_t* __restrict__ qb,
    const char* __restrict__ zp) {
  __shared__ char lds[98304];
  const int tid  = threadIdx.x;
  const int lane = tid & 63;
  const int wid  = tid >> 6;
  const int wr = wid >> 1, wc = wid & 1;   // 4M x 2N

  const int id = blockIdx.x;               // 256 blocks
  const int panel  = id & 3;               // 0..3
  const int n_tile = id >> 2;              // 0..63
  const int m0  = panel * 256;
  const int bn0 = n_tile * 128;
  const int b   = bn0 >> 9;
  const int n0  = bn0 & 511;
  const char* src_c = (const char*)x_t + (size_t)b * NTOK * 2048;
  const char* w_c   = (const char*)wqt;

  const int slotsrc16 = (((tid & 3) ^ ((tid >> 3) & 3)) << 4);
  const int t16 = tid << 4;
  const int r0  = tid >> 2;                // 0..127
  const size_t arow0 = (size_t)(m0 + r0) * 2048 + slotsrc16;

  int cur_tap = -1;
  const char* bp0 = zp;

  const int fr = lane & 15;
  const int rdbase = fr * 64 + (((lane >> 4) ^ ((fr >> 1) & 3)) << 4);

  f32x4 acc[4][4] = {};

  auto upd_tap = [&](int tap) {
    cur_tap = tap;
    const int kd = tap / 9, rem = tap % 9, kh = rem / 3, kw = rem % 3;
    const int n = n0 + r0;
    const int d = (n >> 6) + kd - 1;
    const int h = ((n >> 3) & 7) + kh - 1;
    const int w = (n & 7) + kw - 1;
    const bool ok = ((unsigned)d < 8u) & ((unsigned)h < 8u) & ((unsigned)w < 8u);
    const int nsrc = (d << 6) + (h << 3) + w;
    bp0 = ok ? src_c + (size_t)nsrc * 2048 + slotsrc16 : zp;
  };
  auto stage_half = [&](int tt, int kh, int reg) {  // 3 loads
    const int te = (tt < NKT) ? tt : tt - 2;
    const int tap = te >> 4, kt = te & 15;
    if (tap != cur_tap) upd_tap(tap);
    const size_t gA = (size_t)tap * (1024u * 2048u) + (size_t)(kt * 128 + kh * 64);
    char* La = lds + reg;
    gload_lds16(w_c + gA + arow0,                      La + t16);
    gload_lds16(w_c + gA + arow0 + (size_t)128 * 2048, La + 8192 + t16);
    gload_lds16(bp0 + kt * 128 + kh * 64,              La + 16384 + t16);
  };

#define MFMA16Q(AV, BV)                                                        \
  _Pragma("unroll") for (int i = 0; i < 4; ++i) {                              \
    _Pragma("unroll") for (int j = 0; j < 4; ++j)                              \
        acc[i][j] = __builtin_amdgcn_mfma_f32_16x16x32_f16(                    \
            AV[i], BV[j], acc[i][j], 0, 0, 0);                                 \
  }

  stage_half(0, 0, 0);
  stage_half(0, 1, 24576);
  stage_half(1, 0, 49152);
  asm volatile("s_waitcnt vmcnt(6)\n\ts_barrier" ::: "memory");

#pragma unroll 1
  for (int t = 0; t < NKT; ++t) {
    const int rb = (t & 1) * 49152;               // region: tile t, kh0
    // ---- phase kh0
    {
      const char* sA = lds + rb + wr * 4096 + rdbase;
      const char* sB = lds + rb + 16384 + wc * 4096 + rdbase;
      f16x8 av[4], bv[4];
#pragma unroll
      for (int j = 0; j < 4; ++j) bv[j] = *(const f16x8*)(sB + j * 1024);
#pragma unroll
      for (int i = 0; i < 4; ++i) av[i] = *(const f16x8*)(sA + i * 1024);
      stage_half(t + 1, 1, ((t + 1) & 1) * 49152 + 24576);
      __builtin_amdgcn_s_setprio(1);
      MFMA16Q(av, bv)
      __builtin_amdgcn_s_setprio(0);
      asm volatile("s_waitcnt vmcnt(6)\n\ts_barrier" ::: "memory");
    }
    // ---- phase kh1
    {
      const char* sA = lds + rb + 24576 + wr * 4096 + rdbase;
      const char* sB = lds + rb + 24576 + 16384 + wc * 4096 + rdbase;
      f16x8 av[4], bv[4];
#pragma unroll
      for (int j = 0; j < 4; ++j) bv[j] = *(const f16x8*)(sB + j * 1024);
#pragma unroll
      for (int i = 0; i < 4; ++i) av[i] = *(const f16x8*)(sA + i * 1024);
      stage_half(t + 2, 0, (t & 1) * 49152);
      __builtin_amdgcn_s_setprio(1);
      MFMA16Q(av, bv)
      __builtin_amdgcn_s_setprio(0);
      asm volatile("s_waitcnt vmcnt(6)\n\ts_barrier" ::: "memory");
    }
  }
#undef MFMA16Q

  const int rq = (lane >> 4) << 2;
#pragma unroll
  for (int i = 0; i < 4; ++i) {
    const int c = m0 + wr * 64 + i * 16 + rq;        // 0..1023
    const float4 bs = *(const float4*)&bq[c];
#pragma unroll
    for (int j = 0; j < 4; ++j) {
      const int n = n0 + wc * 64 + j * 16 + fr;
      f16x4 pk;
      pk[0] = (f16_t)(acc[i][j][0] + bs.x);
      pk[1] = (f16_t)(acc[i][j][1] + bs.y);
      pk[2] = (f16_t)(acc[i][j][2] + bs.z);
      pk[3] = (f16_t)(acc[i][j][3] + bs.w);
      *(f16x4*)(qb + ((size_t)(b * NTOK + n)) * CCH + c) = pk;
    }
  }
}

// ---------------- generic gemm_bt for attention: C = A * Bt^T (+resid) -------
__global__ __launch_bounds__(256) void attn_gemm_kernel(
    const f16_t* __restrict__ A, const f16_t* __restrict__ Bt,
    float* __restrict__ Cout, const float* __restrict__ resid,
    const int Kdim, const int ldc,
    const size_t strideA, const size_t strideB, const size_t strideC) {
  __shared__ f16_t As[128 * 64];
  __shared__ f16_t Bs[128 * 64];
  char* As_c = (char*)As;
  char* Bs_c = (char*)Bs;

  const int tid  = threadIdx.x;
  const int lane = tid & 63;
  const int wave = tid >> 6;
  const int wr = wave >> 1, wc = wave & 1;
  const int bz = blockIdx.z;
  const int m0 = blockIdx.y * 128;
  const int n0 = blockIdx.x * 128;

  const f16_t* Ab = A + (size_t)bz * strideA;
  const f16_t* Bb = Bt + (size_t)bz * strideB;

  const int rowb = tid >> 3;
  const int colb = (tid & 7) * 16;

  const char* ap[4];
  const char* bp[4];
#pragma unroll
  for (int r = 0; r < 4; ++r) {
    const int row = r * 32 + rowb;
    ap[r] = (const char*)(Ab + (size_t)(m0 + row) * Kdim) + colb;
    bp[r] = (const char*)(Bb + (size_t)(n0 + row) * Kdim) + colb;
  }

  f32x4 acc[4][4] = {};
  const int fr = lane & 15;
  const int fk = (lane >> 4) << 3;

  for (int k0 = 0; k0 < Kdim; k0 += 64) {
#pragma unroll
    for (int r = 0; r < 4; ++r)
      gload_lds16(ap[r], As_c + r * 4096 + wave * 1024);
#pragma unroll
    for (int r = 0; r < 4; ++r)
      gload_lds16(bp[r], Bs_c + r * 4096 + wave * 1024);
#pragma unroll
    for (int r = 0; r < 4; ++r) { ap[r] += 128; bp[r] += 128; }
    __syncthreads();
#pragma unroll
    for (int ks = 0; ks < 2; ++ks) {
      const int kc = ks * 32 + fk;
      f16x8 av[4], bv[4];
#pragma unroll
      for (int i = 0; i < 4; ++i)
        av[i] = *(const f16x8*)&As[(wr * 64 + i * 16 + fr) * 64 + kc];
#pragma unroll
      for (int i = 0; i < 4; ++i)
        bv[i] = *(const f16x8*)&Bs[(wc * 64 + i * 16 + fr) * 64 + kc];
#pragma unroll
      for (int i = 0; i < 4; ++i)
#pragma unroll
        for (int j = 0; j < 4; ++j)
          acc[i][j] = __builtin_amdgcn_mfma_f32_16x16x32_f16(av[i], bv[j], acc[i][j], 0, 0, 0);
    }
    __syncthreads();
  }

  const int mo = m0 + wr * 64 + ((lane >> 4) << 2);
  const int nn = n0 + wc * 64 + (lane & 15);
  float* Cb = Cout + (size_t)bz * strideC;
  const float* Rb = resid ? resid + (size_t)bz * strideC : nullptr;
#pragma unroll
  for (int i = 0; i < 4; ++i) {
#pragma unroll
    for (int j = 0; j < 4; ++j) {
      const int n = nn + j * 16;
#pragma unroll
      for (int reg = 0; reg < 4; ++reg) {
        const int m = mo + i * 16 + reg;
        float v = acc[i][j][reg];
        if (Rb) v += Rb[(size_t)m * ldc + n];
        Cb[(size_t)m * ldc + n] = v;
      }
    }
  }
}

// ---------------- row softmax: S fp32 [rows][512] -> P f16 -------------------
__global__ __launch_bounds__(256) void softmax_kernel(
    const float* __restrict__ S, f16_t* __restrict__ P) {
  const int row  = blockIdx.x * 4 + (threadIdx.x >> 6);
  const int lane = threadIdx.x & 63;
  const float* s = S + (size_t)row * 512;
  const float4 v0 = ((const float4*)s)[lane];
  const float4 v1 = ((const float4*)s)[64 + lane];
  float m = fmaxf(fmaxf(fmaxf(v0.x, v0.y), fmaxf(v0.z, v0.w)),
                  fmaxf(fmaxf(v1.x, v1.y), fmaxf(v1.z, v1.w)));
#pragma unroll
  for (int o = 32; o; o >>= 1) m = fmaxf(m, __shfl_xor(m, o, 64));
  float e[8];
  e[0] = __expf(v0.x - m); e[1] = __expf(v0.y - m);
  e[2] = __expf(v0.z - m); e[3] = __expf(v0.w - m);
  e[4] = __expf(v1.x - m); e[5] = __expf(v1.y - m);
  e[6] = __expf(v1.z - m); e[7] = __expf(v1.w - m);
  float sum = ((e[0] + e[1]) + (e[2] + e[3])) + ((e[4] + e[5]) + (e[6] + e[7]));
#pragma unroll
  for (int o = 32; o; o >>= 1) sum += __shfl_xor(sum, o, 64);
  const float r = 1.0f / sum;
  f16_t* p = P + (size_t)row * 512;
  f16x4 o0, o1;
  o0[0] = (f16_t)(e[0] * r); o0[1] = (f16_t)(e[1] * r);
  o0[2] = (f16_t)(e[2] * r); o0[3] = (f16_t)(e[3] * r);
  o1[0] = (f16_t)(e[4] * r); o1[1] = (f16_t)(e[5] * r);
  o1[2] = (f16_t)(e[6] * r); o1[3] = (f16_t)(e[7] * r);
  ((f16x4*)p)[lane] = o0;
  ((f16x4*)p)[64 + lane] = o1;
}

// -----------------------------------------------------------------------------
extern "C" void kernel_launch(void* const* d_in, const int* in_sizes, int n_in,
                              void* d_out, int out_size, void* d_ws, size_t ws_size,
                              hipStream_t stream) {
  (void)in_sizes; (void)n_in; (void)out_size;
  const float* x  = (const float*)d_in[0];
  const float* y  = (const float*)d_in[1];
  const float* wq = (const float*)d_in[2];
  const float* bq = (const float*)d_in[3];
  const float* wk = (const float*)d_in[4];
  const float* bk = (const float*)d_in[5];
  const float* wv = (const float*)d_in[6];
  const float* bv = (const float*)d_in[7];

  char* ws = (char*)d_ws;
  size_t off = 0;
  auto alloc = [&](size_t bytes) {
    void* p = ws + off;
    off = (off + bytes + 255) & ~(size_t)255;
    return p;
  };
  const size_t act_b = (size_t)BATCH * NTOK * CCH * 2;  // 16 MB
  f16_t* x_t    = (f16_t*)alloc(act_b);
  f16_t* y_t    = (f16_t*)alloc(act_b);
  f16_t* wkv    = (f16_t*)alloc((size_t)27 * 2048 * 1024 * 2);   // 113 MB
  f16_t* wqt    = (f16_t*)alloc((size_t)27 * 1024 * 1024 * 2);   //  57 MB
  float* bkv    = (float*)alloc(2048 * 4);
  f16_t* qb     = (f16_t*)alloc(act_b);
  f16_t* kb     = (f16_t*)alloc(act_b);
  f16_t* vb     = (f16_t*)alloc(act_b);
  float* scores = (float*)alloc((size_t)BATCH * 512 * 512 * 4);  // 16 MB
  f16_t* Pb     = (f16_t*)alloc((size_t)BATCH * 512 * 512 * 2);  //  8 MB
  char*  zerop  = (char*)alloc(4096);
  if (off > ws_size) return;

  const dim3 blk(256);
  hipMemsetAsync(zerop, 0, 4096, stream);
  cast_transpose_kernel<<<dim3(8, 16, 16), blk, 0, stream>>>(x, x_t);
  cast_transpose_kernel<<<dim3(8, 16, 16), blk, 0, stream>>>(y, y_t);

  wtrans_kernel<<<dim3(1024, 16), blk, 0, stream>>>(wk, wkv, 0, 2048);
  wtrans_kernel<<<dim3(1024, 16), blk, 0, stream>>>(wv, wkv, 1024, 2048);
  wtrans_kernel<<<dim3(1024, 16), blk, 0, stream>>>(wq, wqt, 0, 1024);
  hipMemcpyAsync(bkv,        bk, 1024 * 4, hipMemcpyDeviceToDevice, stream);
  hipMemcpyAsync(bkv + 1024, bv, 1024 * 4, hipMemcpyDeviceToDevice, stream);

  conv_kv_kernel<<<dim3(256), dim3(512), 0, stream>>>(y_t, wkv, bkv, kb, vb, zerop);
  conv_q_kernel<<<dim3(256), dim3(512), 0, stream>>>(x_t, wqt, bq, qb, zerop);

  // scores[b][n][m] = sum_c q[b][n][c] * k[b][m][c]
  attn_gemm_kernel<<<dim3(4, 4, 16), blk, 0, stream>>>(
      qb, kb, scores, nullptr, 1024, 512,
      (size_t)512 * 1024, (size_t)512 * 1024, (size_t)512 * 512);
  softmax_kernel<<<dim3(BATCH * 512 / 4), blk, 0, stream>>>(scores, Pb);
  // out[b][c][n] = sum_m v[b][c][m] * P[b][n][m] + x[b][c][n]
  attn_gemm_kernel<<<dim3(4, 8, 16), blk, 0, stream>>>(
      vb, Pb, (float*)d_out, x, 512, 512,
      (size_t)1024 * 512, (size_t)512 * 512, (size_t)1024 * 512);
}